// Round 1
// baseline (329.972 us; speedup 1.0000x reference)
//
#include <hip/hip_runtime.h>
#include <hip/hip_bf16.h>

// HorizonTemporalSelfAttention: multi-scale deformable attention
// bs=2, nq=16384, E=256, NH=8, NL=4, NP=4, d=32, total tokens=21760
// shapes (W,H): (128,128),(64,64),(32,32),(16,16), bases 0,16384,20480,21504
//
// Pipeline:
//  K1 convert: query f32 -> fp16 (qh), Wcat=[W_off;W_attn] f32 -> fp16 (wh)
//  K2 gemm   : logits[32768][384] = qh @ wh^T + bias  (fp16 MFMA 16x16x32, f32 acc)
//  K3 sample : per (b,h,q): softmax(16 attn logits), 16 bilinear taps from value,
//              LDS transpose, coalesced write to out[b][h*32+c][q]

typedef __attribute__((ext_vector_type(4))) float    float4v;
typedef __attribute__((ext_vector_type(8))) _Float16 half8;
typedef __attribute__((ext_vector_type(4))) _Float16 half4;

#define NQ    16384
#define NTOK  21760
#define NLOG  384

// ---------------- K1: convert ----------------
// query: 2*16384*256 = 8388608 f32 -> 2097152 float4 units
// Wcat : 384*256 = 98304 f32      -> 24576 float4 units
__global__ __launch_bounds__(256) void convert_kernel(
    const float* __restrict__ q, const float* __restrict__ Woff,
    const float* __restrict__ Wattn,
    _Float16* __restrict__ qh, _Float16* __restrict__ wh) {
  int i = blockIdx.x * 256 + threadIdx.x;
  if (i < 2097152) {
    float4v v = ((const float4v*)q)[i];
    half4 o;
    o[0] = (_Float16)v[0]; o[1] = (_Float16)v[1];
    o[2] = (_Float16)v[2]; o[3] = (_Float16)v[3];
    ((half4*)qh)[i] = o;
  } else {
    int j = i - 2097152;                 // [0, 24576)
    int n = j >> 6;                      // Wcat row 0..383
    int k4 = j & 63;
    const float* src = (n < 256) ? (Woff + (size_t)n * 256)
                                 : (Wattn + (size_t)(n - 256) * 256);
    float4v v = *(const float4v*)(src + k4 * 4);
    half4 o;
    o[0] = (_Float16)v[0]; o[1] = (_Float16)v[1];
    o[2] = (_Float16)v[2]; o[3] = (_Float16)v[3];
    ((half4*)wh)[j] = o;
  }
}

// ---------------- K2: GEMM via fp16 MFMA ----------------
// Per wave: M=32 (two 16-row subtiles), N=64 (four 16-col subtiles), K=256.
// Fragments loaded directly from global (W L2-resident, qh cached).
// A frag: lane holds A[m = lane&15][k = (lane>>4)*8 + j], j=0..7
// B frag: lane holds B[k = (lane>>4)*8 + j][n = lane&15]  (W row-major == B^T)
// D     : row = (lane>>4)*4 + reg, col = lane&15
__global__ __launch_bounds__(256) void gemm_kernel(
    const _Float16* __restrict__ qh, const _Float16* __restrict__ wh,
    const float* __restrict__ boff, const float* __restrict__ battn,
    float* __restrict__ logits) {
  const int lane = threadIdx.x & 63;
  const int wv   = threadIdx.x >> 6;
  const int quad = lane >> 4;
  const int r    = lane & 15;
  const int m0 = blockIdx.x * 128 + wv * 32;
  const int n0 = blockIdx.y * 64;

  const _Float16* A0 = qh + (size_t)(m0 + r) * 256 + quad * 8;
  const _Float16* B0 = wh + (size_t)(n0 + r) * 256 + quad * 8;

  float4v acc[2][4];
#pragma unroll
  for (int i = 0; i < 2; ++i)
#pragma unroll
    for (int nt = 0; nt < 4; ++nt) acc[i][nt] = (float4v){0.f, 0.f, 0.f, 0.f};

#pragma unroll
  for (int kt = 0; kt < 8; ++kt) {
    const int ko = kt * 32;
    half8 a0 = *(const half8*)(A0 + ko);
    half8 a1 = *(const half8*)(A0 + 16 * 256 + ko);
    half8 b0 = *(const half8*)(B0 + ko);
    half8 b1 = *(const half8*)(B0 + 16 * 256 + ko);
    half8 b2 = *(const half8*)(B0 + 32 * 256 + ko);
    half8 b3 = *(const half8*)(B0 + 48 * 256 + ko);
    acc[0][0] = __builtin_amdgcn_mfma_f32_16x16x32_f16(a0, b0, acc[0][0], 0, 0, 0);
    acc[0][1] = __builtin_amdgcn_mfma_f32_16x16x32_f16(a0, b1, acc[0][1], 0, 0, 0);
    acc[0][2] = __builtin_amdgcn_mfma_f32_16x16x32_f16(a0, b2, acc[0][2], 0, 0, 0);
    acc[0][3] = __builtin_amdgcn_mfma_f32_16x16x32_f16(a0, b3, acc[0][3], 0, 0, 0);
    acc[1][0] = __builtin_amdgcn_mfma_f32_16x16x32_f16(a1, b0, acc[1][0], 0, 0, 0);
    acc[1][1] = __builtin_amdgcn_mfma_f32_16x16x32_f16(a1, b1, acc[1][1], 0, 0, 0);
    acc[1][2] = __builtin_amdgcn_mfma_f32_16x16x32_f16(a1, b2, acc[1][2], 0, 0, 0);
    acc[1][3] = __builtin_amdgcn_mfma_f32_16x16x32_f16(a1, b3, acc[1][3], 0, 0, 0);
  }

#pragma unroll
  for (int i = 0; i < 2; ++i) {
    const int mb = m0 + i * 16 + quad * 4;
#pragma unroll
    for (int nt = 0; nt < 4; ++nt) {
      const int n = n0 + nt * 16 + r;
      const float bias = (n < 256) ? boff[n] : battn[n - 256];
#pragma unroll
      for (int reg = 0; reg < 4; ++reg)
        logits[(size_t)(mb + reg) * NLOG + n] = acc[i][nt][reg] + bias;
    }
  }
}

// ---------------- K3: sampling ----------------
// grid (512, 8, 2) = (q-tile of 32, head, batch); block 256 threads.
// thread: c8 = tid&7 -> channels c8*4..c8*4+3 ; qi = tid>>3 -> query in tile.
__global__ __launch_bounds__(256) void sample_kernel(
    const float* __restrict__ value, const float* __restrict__ refp,
    const float* __restrict__ logits, float* __restrict__ out) {
  const int qt = blockIdx.x, h = blockIdx.y, b = blockIdx.z;
  const int tid = threadIdx.x;
  const int c8 = tid & 7;
  const int qi = tid >> 3;
  const int q  = qt * 32 + qi;
  const size_t bq = (size_t)b * NQ + q;
  const float* lg = logits + bq * NLOG;

  // attn softmax over 16 (l*4+p) logits
  float4v al4[4];
#pragma unroll
  for (int i = 0; i < 4; ++i)
    al4[i] = *(const float4v*)(lg + 256 + h * 16 + i * 4);
  float mx = -1e30f;
#pragma unroll
  for (int i = 0; i < 4; ++i)
#pragma unroll
    for (int j = 0; j < 4; ++j) mx = fmaxf(mx, al4[i][j]);
  float ssum = 0.f;
#pragma unroll
  for (int i = 0; i < 4; ++i)
#pragma unroll
    for (int j = 0; j < 4; ++j) {
      float e = __expf(al4[i][j] - mx);
      al4[i][j] = e;
      ssum += e;
    }
  const float inv = 1.0f / ssum;

  // offsets (32 floats, layout l*8+p*2+xy) and reference points (8 floats)
  float4v offv[8];
#pragma unroll
  for (int i = 0; i < 8; ++i)
    offv[i] = *(const float4v*)(lg + h * 32 + i * 4);
  float4v rp0 = *(const float4v*)(refp + bq * 8);
  float4v rp1 = *(const float4v*)(refp + bq * 8 + 4);
  const float rpx[4] = {rp0[0], rp0[2], rp1[0], rp1[2]};
  const float rpy[4] = {rp0[1], rp0[3], rp1[1], rp1[3]};

  const float* vb = value + (size_t)b * NTOK * 256 + h * 32 + c8 * 4;
  float4v acc = (float4v){0.f, 0.f, 0.f, 0.f};

  const int   Wl[4]   = {128, 64, 32, 16};
  const int   base[4] = {0, 16384, 20480, 21504};

#pragma unroll
  for (int l = 0; l < 4; ++l) {
    const int   W  = Wl[l];
    const float fW = (float)W;
    const float* vlev = vb + (size_t)base[l] * 256;
#pragma unroll
    for (int p = 0; p < 4; ++p) {
      const float ox = offv[l * 2 + (p >> 1)][(p & 1) * 2];
      const float oy = offv[l * 2 + (p >> 1)][(p & 1) * 2 + 1];
      // pixel coords: (ref + off/shape)*2-1 through grid_sample == ref*W + off - 0.5
      const float x = rpx[p] * fW + ox - 0.5f;
      const float y = rpy[p] * fW + oy - 0.5f;
      const float xf = floorf(x), yf = floorf(y);
      const float fx = x - xf, fy = y - yf;
      const int ix = (int)xf, iy = (int)yf;
      const bool vx0 = (unsigned)ix < (unsigned)W;
      const bool vx1 = (unsigned)(ix + 1) < (unsigned)W;
      const bool vy0 = (unsigned)iy < (unsigned)W;
      const bool vy1 = (unsigned)(iy + 1) < (unsigned)W;
      float4v sv = (float4v){0.f, 0.f, 0.f, 0.f};
      if (vy0) {
        const float* row = vlev + (size_t)iy * (W * 256);
        if (vx0) sv += ((1.f - fx) * (1.f - fy)) * *(const float4v*)(row + ix * 256);
        if (vx1) sv += (fx * (1.f - fy)) * *(const float4v*)(row + (ix + 1) * 256);
      }
      if (vy1) {
        const float* row = vlev + (size_t)(iy + 1) * (W * 256);
        if (vx0) sv += ((1.f - fx) * fy) * *(const float4v*)(row + ix * 256);
        if (vx1) sv += (fx * fy) * *(const float4v*)(row + (ix + 1) * 256);
      }
      acc += al4[l][p] * sv;
    }
  }

  // LDS transpose -> coalesced out[b][h*32+c][q]
  __shared__ float sm[32][33];
#pragma unroll
  for (int j = 0; j < 4; ++j) sm[c8 * 4 + j][qi] = acc[j] * inv;
  __syncthreads();
  const size_t obase = ((size_t)b * 256 + h * 32) * NQ + qt * 32;
#pragma unroll
  for (int i = 0; i < 4; ++i) {
    const int idx = i * 256 + tid;
    const int c = idx >> 5, qq = idx & 31;
    out[obase + (size_t)c * NQ + qq] = sm[c][qq];
  }
}

extern "C" void kernel_launch(void* const* d_in, const int* in_sizes, int n_in,
                              void* d_out, int out_size, void* d_ws, size_t ws_size,
                              hipStream_t stream) {
  const float* query = (const float*)d_in[0];
  const float* value = (const float*)d_in[1];
  const float* refp  = (const float*)d_in[2];
  const float* Woff  = (const float*)d_in[3];
  const float* boff  = (const float*)d_in[4];
  const float* Wattn = (const float*)d_in[5];
  const float* battn = (const float*)d_in[6];
  float* out = (float*)d_out;

  char* ws = (char*)d_ws;
  _Float16* qh     = (_Float16*)ws;                    // 16,777,216 B
  _Float16* wh     = (_Float16*)(ws + 16777216);       //    196,608 B
  float*    logits = (float*)(ws + 16973824);          // 50,331,648 B

  convert_kernel<<<8288, 256, 0, stream>>>(query, Woff, Wattn, qh, wh);
  gemm_kernel<<<dim3(256, 6), 256, 0, stream>>>(qh, wh, boff, battn, logits);
  sample_kernel<<<dim3(512, 8, 2), 256, 0, stream>>>(value, refp, logits, out);
}

// Round 2
// 302.364 us; speedup vs baseline: 1.0913x; 1.0913x over previous
//
#include <hip/hip_runtime.h>
#include <hip/hip_bf16.h>

// HorizonTemporalSelfAttention: multi-scale deformable attention
// bs=2, nq=16384, E=256, NH=8, NL=4, NP=4, d=32, total tokens=21760
//
// R2: fp16 value (halve gather traffic, L2-resident), LDS-staged MFMA GEMM
//  K1 convert: query,value,Wcat f32 -> fp16
//  K2 gemm   : logits[32768][384] = qh @ wh^T + bias (LDS-staged, 128x128 tile)
//  K3 sample : softmax + 16 bilinear fp16 taps + LDS transpose store

typedef __attribute__((ext_vector_type(4))) float    float4v;
typedef __attribute__((ext_vector_type(8))) _Float16 half8;
typedef __attribute__((ext_vector_type(4))) _Float16 half4;

#define NQ    16384
#define NTOK  21760
#define NLOG  384

#define N_Q4  2097152   // query f32 in float4 units
#define N_V4  2785280   // value f32 in float4 units
#define N_W4  24576     // Wcat  f32 in float4 units

// ---------------- K1: convert f32 -> f16 ----------------
__global__ __launch_bounds__(256) void convert_kernel(
    const float* __restrict__ q, const float* __restrict__ val,
    const float* __restrict__ Woff, const float* __restrict__ Wattn,
    _Float16* __restrict__ qh, _Float16* __restrict__ vh,
    _Float16* __restrict__ wh) {
  int i = blockIdx.x * 256 + threadIdx.x;
  float4v v;
  half4* dst;
  if (i < N_Q4) {
    v = ((const float4v*)q)[i];
    dst = ((half4*)qh) + i;
  } else if (i < N_Q4 + N_V4) {
    int j = i - N_Q4;
    v = ((const float4v*)val)[j];
    dst = ((half4*)vh) + j;
  } else {
    int j = i - (N_Q4 + N_V4);           // [0, 24576)
    int n = j >> 6;                      // Wcat row 0..383
    int k4 = j & 63;
    const float* src = (n < 256) ? (Woff + (size_t)n * 256)
                                 : (Wattn + (size_t)(n - 256) * 256);
    v = *(const float4v*)(src + k4 * 4);
    dst = ((half4*)wh) + j;
  }
  half4 o;
  o[0] = (_Float16)v[0]; o[1] = (_Float16)v[1];
  o[2] = (_Float16)v[2]; o[3] = (_Float16)v[3];
  *dst = o;
}

// ---------------- K2: LDS-staged fp16 MFMA GEMM ----------------
// grid (256, 3): block tile M=128 (blockIdx.x), N=128 (blockIdx.y), K=256.
// 4 waves in 2x2 -> wave tile 64x64 = 4x4 subtiles of 16x16, f32 acc.
// LDS: As/Bs [128][88] halves (stride 88 -> 16B-aligned rows, 2-way-max banks).
#define LDSTR 88
__global__ __launch_bounds__(256) void gemm_kernel(
    const _Float16* __restrict__ qh, const _Float16* __restrict__ wh,
    const float* __restrict__ boff, const float* __restrict__ battn,
    float* __restrict__ logits) {
  __shared__ _Float16 As[128 * LDSTR];
  __shared__ _Float16 Bs[128 * LDSTR];

  const int tid  = threadIdx.x;
  const int lane = tid & 63;
  const int wv   = tid >> 6;
  const int wm   = wv >> 1, wn = wv & 1;
  const int quad = lane >> 4;
  const int r    = lane & 15;
  const int blockM = blockIdx.x * 128;
  const int n0     = blockIdx.y * 128;

  float4v acc[4][4];
#pragma unroll
  for (int i = 0; i < 4; ++i)
#pragma unroll
    for (int j = 0; j < 4; ++j) acc[i][j] = (float4v){0.f, 0.f, 0.f, 0.f};

  for (int kc = 0; kc < 4; ++kc) {
    const int k0 = kc * 64;
    if (kc) __syncthreads();
#pragma unroll
    for (int i = 0; i < 4; ++i) {
      int u = i * 256 + tid;
      int row = u >> 3, c8 = u & 7;
      *(half8*)&As[row * LDSTR + c8 * 8] =
          *(const half8*)(qh + (size_t)(blockM + row) * 256 + k0 + c8 * 8);
      *(half8*)&Bs[row * LDSTR + c8 * 8] =
          *(const half8*)(wh + (size_t)(n0 + row) * 256 + k0 + c8 * 8);
    }
    __syncthreads();

#pragma unroll
    for (int kf = 0; kf < 2; ++kf) {
      const int ko = kf * 32 + quad * 8;
      half8 af[4], bf[4];
#pragma unroll
      for (int mi = 0; mi < 4; ++mi)
        af[mi] = *(const half8*)&As[(wm * 64 + mi * 16 + r) * LDSTR + ko];
#pragma unroll
      for (int ni = 0; ni < 4; ++ni)
        bf[ni] = *(const half8*)&Bs[(wn * 64 + ni * 16 + r) * LDSTR + ko];
#pragma unroll
      for (int mi = 0; mi < 4; ++mi)
#pragma unroll
        for (int ni = 0; ni < 4; ++ni)
          acc[mi][ni] = __builtin_amdgcn_mfma_f32_16x16x32_f16(af[mi], bf[ni], acc[mi][ni], 0, 0, 0);
    }
  }

#pragma unroll
  for (int mi = 0; mi < 4; ++mi) {
    const int mb = blockM + wm * 64 + mi * 16 + quad * 4;
#pragma unroll
    for (int ni = 0; ni < 4; ++ni) {
      const int n = n0 + wn * 64 + ni * 16 + r;
      const float bias = (n < 256) ? boff[n] : battn[n - 256];
#pragma unroll
      for (int reg = 0; reg < 4; ++reg)
        logits[(size_t)(mb + reg) * NLOG + n] = acc[mi][ni][reg] + bias;
    }
  }
}

// ---------------- K3: sampling (fp16 value) ----------------
static __device__ inline float4v h4f(half4 h) {
  return (float4v){(float)h[0], (float)h[1], (float)h[2], (float)h[3]};
}

__global__ __launch_bounds__(256) void sample_kernel(
    const _Float16* __restrict__ vh, const float* __restrict__ refp,
    const float* __restrict__ logits, float* __restrict__ out) {
  const int qt = blockIdx.x, h = blockIdx.y, b = blockIdx.z;
  const int tid = threadIdx.x;
  const int c8 = tid & 7;
  const int qi = tid >> 3;
  const int q  = qt * 32 + qi;
  const size_t bq = (size_t)b * NQ + q;
  const float* lg = logits + bq * NLOG;

  // attn softmax over 16 (l*4+p) logits
  float4v al4[4];
#pragma unroll
  for (int i = 0; i < 4; ++i)
    al4[i] = *(const float4v*)(lg + 256 + h * 16 + i * 4);
  float mx = -1e30f;
#pragma unroll
  for (int i = 0; i < 4; ++i)
#pragma unroll
    for (int j = 0; j < 4; ++j) mx = fmaxf(mx, al4[i][j]);
  float ssum = 0.f;
#pragma unroll
  for (int i = 0; i < 4; ++i)
#pragma unroll
    for (int j = 0; j < 4; ++j) {
      float e = __expf(al4[i][j] - mx);
      al4[i][j] = e;
      ssum += e;
    }
  const float inv = 1.0f / ssum;

  // offsets (32 floats, layout l*8+p*2+xy) and reference points (8 floats)
  float4v offv[8];
#pragma unroll
  for (int i = 0; i < 8; ++i)
    offv[i] = *(const float4v*)(lg + h * 32 + i * 4);
  float4v rp0 = *(const float4v*)(refp + bq * 8);
  float4v rp1 = *(const float4v*)(refp + bq * 8 + 4);
  const float rpx[4] = {rp0[0], rp0[2], rp1[0], rp1[2]};
  const float rpy[4] = {rp0[1], rp0[3], rp1[1], rp1[3]};

  const _Float16* vb = vh + (size_t)b * NTOK * 256 + h * 32 + c8 * 4;
  float4v acc = (float4v){0.f, 0.f, 0.f, 0.f};

  const int base[4] = {0, 16384, 20480, 21504};

#pragma unroll
  for (int l = 0; l < 4; ++l) {
    const int   W  = 128 >> l;
    const float fW = (float)W;
    const _Float16* vlev = vb + (size_t)base[l] * 256;
#pragma unroll
    for (int p = 0; p < 4; ++p) {
      const float ox = offv[l * 2 + (p >> 1)][(p & 1) * 2];
      const float oy = offv[l * 2 + (p >> 1)][(p & 1) * 2 + 1];
      // (ref + off/shape)*2-1 through grid_sample == ref*W + off - 0.5
      const float x = rpx[p] * fW + ox - 0.5f;
      const float y = rpy[p] * fW + oy - 0.5f;
      const float xf = floorf(x), yf = floorf(y);
      const float fx = x - xf, fy = y - yf;
      const int ix = (int)xf, iy = (int)yf;
      const bool vx0 = (unsigned)ix < (unsigned)W;
      const bool vx1 = (unsigned)(ix + 1) < (unsigned)W;
      const bool vy0 = (unsigned)iy < (unsigned)W;
      const bool vy1 = (unsigned)(iy + 1) < (unsigned)W;
      float4v sv = (float4v){0.f, 0.f, 0.f, 0.f};
      if (vy0) {
        const _Float16* row = vlev + (size_t)iy * (W * 256);
        if (vx0) sv += ((1.f - fx) * (1.f - fy)) * h4f(*(const half4*)(row + ix * 256));
        if (vx1) sv += (fx * (1.f - fy)) * h4f(*(const half4*)(row + (ix + 1) * 256));
      }
      if (vy1) {
        const _Float16* row = vlev + (size_t)(iy + 1) * (W * 256);
        if (vx0) sv += ((1.f - fx) * fy) * h4f(*(const half4*)(row + ix * 256));
        if (vx1) sv += (fx * fy) * h4f(*(const half4*)(row + (ix + 1) * 256));
      }
      acc += al4[l][p] * sv;
    }
  }

  // LDS transpose -> coalesced out[b][h*32+c][q]
  __shared__ float sm[32][33];
#pragma unroll
  for (int j = 0; j < 4; ++j) sm[c8 * 4 + j][qi] = acc[j] * inv;
  __syncthreads();
  const size_t obase = ((size_t)b * 256 + h * 32) * NQ + qt * 32;
#pragma unroll
  for (int i = 0; i < 4; ++i) {
    const int idx = i * 256 + tid;
    const int c = idx >> 5, qq = idx & 31;
    out[obase + (size_t)c * NQ + qq] = sm[c][qq];
  }
}

extern "C" void kernel_launch(void* const* d_in, const int* in_sizes, int n_in,
                              void* d_out, int out_size, void* d_ws, size_t ws_size,
                              hipStream_t stream) {
  const float* query = (const float*)d_in[0];
  const float* value = (const float*)d_in[1];
  const float* refp  = (const float*)d_in[2];
  const float* Woff  = (const float*)d_in[3];
  const float* boff  = (const float*)d_in[4];
  const float* Wattn = (const float*)d_in[5];
  const float* battn = (const float*)d_in[6];
  float* out = (float*)d_out;

  char* ws = (char*)d_ws;
  _Float16* qh     = (_Float16*)ws;                    // 16,777,216 B
  _Float16* vh     = (_Float16*)(ws + 16777216);       // 22,282,240 B
  _Float16* wh     = (_Float16*)(ws + 39059456);       //    196,608 B
  float*    logits = (float*)(ws + 39256064);          // 50,331,648 B

  convert_kernel<<<19168, 256, 0, stream>>>(query, value, Woff, Wattn, qh, vh, wh);
  gemm_kernel<<<dim3(256, 3), 256, 0, stream>>>(qh, wh, boff, battn, logits);
  sample_kernel<<<dim3(512, 8, 2), 256, 0, stream>>>(vh, refp, logits, out);
}

// Round 3
// 228.448 us; speedup vs baseline: 1.4444x; 1.3236x over previous
//
#include <hip/hip_runtime.h>
#include <hip/hip_bf16.h>

// HorizonTemporalSelfAttention: multi-scale deformable attention
// bs=2, nq=16384, E=256, NH=8, NL=4, NP=4, d=32, total tokens=21760
//
// R3: branchless sampler (clamped idx + zeroed weights), 4 lanes/(q,h) with
//     16B half8 taps, attn folded into tap weights; GEMM stages A from f32.

typedef __attribute__((ext_vector_type(4))) float    float4v;
typedef __attribute__((ext_vector_type(8))) _Float16 half8;
typedef __attribute__((ext_vector_type(4))) _Float16 half4;

#define NQ    16384
#define NTOK  21760
#define NLOG  384

#define N_V4  2785280   // value f32 in float4 units
#define N_W4  24576     // Wcat  f32 in float4 units

// ---------------- K1: convert value + Wcat f32 -> f16 ----------------
__global__ __launch_bounds__(256) void convert_kernel(
    const float* __restrict__ val,
    const float* __restrict__ Woff, const float* __restrict__ Wattn,
    _Float16* __restrict__ vh, _Float16* __restrict__ wh) {
  int i = blockIdx.x * 256 + threadIdx.x;
  float4v v;
  half4* dst;
  if (i < N_V4) {
    v = ((const float4v*)val)[i];
    dst = ((half4*)vh) + i;
  } else {
    int j = i - N_V4;                    // [0, 24576)
    int n = j >> 6;                      // Wcat row 0..383
    int k4 = j & 63;
    const float* src = (n < 256) ? (Woff + (size_t)n * 256)
                                 : (Wattn + (size_t)(n - 256) * 256);
    v = *(const float4v*)(src + k4 * 4);
    dst = ((half4*)wh) + j;
  }
  half4 o;
  o[0] = (_Float16)v[0]; o[1] = (_Float16)v[1];
  o[2] = (_Float16)v[2]; o[3] = (_Float16)v[3];
  *dst = o;
}

// ---------------- K2: LDS-staged fp16 MFMA GEMM ----------------
// grid (256, 3): block tile M=128, N=128, K=256 (4 chunks of 64).
// A staged from f32 query with on-the-fly f16 convert.
#define LDSTR 88
__global__ __launch_bounds__(256) void gemm_kernel(
    const float* __restrict__ qf, const _Float16* __restrict__ wh,
    const float* __restrict__ boff, const float* __restrict__ battn,
    float* __restrict__ logits) {
  __shared__ _Float16 As[128 * LDSTR];
  __shared__ _Float16 Bs[128 * LDSTR];

  const int tid  = threadIdx.x;
  const int lane = tid & 63;
  const int wv   = tid >> 6;
  const int wm   = wv >> 1, wn = wv & 1;
  const int quad = lane >> 4;
  const int r    = lane & 15;
  const int blockM = blockIdx.x * 128;
  const int n0     = blockIdx.y * 128;

  float4v acc[4][4];
#pragma unroll
  for (int i = 0; i < 4; ++i)
#pragma unroll
    for (int j = 0; j < 4; ++j) acc[i][j] = (float4v){0.f, 0.f, 0.f, 0.f};

  for (int kc = 0; kc < 4; ++kc) {
    const int k0 = kc * 64;
    if (kc) __syncthreads();
    // A: 128 rows x 64 k of f32 = 2048 float4, convert -> half4 into LDS
#pragma unroll
    for (int it = 0; it < 8; ++it) {
      int idx = it * 256 + tid;
      int row = idx >> 4, k4 = idx & 15;
      float4v v = *(const float4v*)(qf + (size_t)(blockM + row) * 256 + k0 + k4 * 4);
      half4 o;
      o[0] = (_Float16)v[0]; o[1] = (_Float16)v[1];
      o[2] = (_Float16)v[2]; o[3] = (_Float16)v[3];
      *(half4*)&As[row * LDSTR + k4 * 4] = o;
    }
    // B: 128 rows x 64 k f16 = 1024 half8
#pragma unroll
    for (int it = 0; it < 4; ++it) {
      int idx = it * 256 + tid;
      int row = idx >> 3, c8 = idx & 7;
      *(half8*)&Bs[row * LDSTR + c8 * 8] =
          *(const half8*)(wh + (size_t)(n0 + row) * 256 + k0 + c8 * 8);
    }
    __syncthreads();

#pragma unroll
    for (int kf = 0; kf < 2; ++kf) {
      const int ko = kf * 32 + quad * 8;
      half8 af[4], bf[4];
#pragma unroll
      for (int mi = 0; mi < 4; ++mi)
        af[mi] = *(const half8*)&As[(wm * 64 + mi * 16 + r) * LDSTR + ko];
#pragma unroll
      for (int ni = 0; ni < 4; ++ni)
        bf[ni] = *(const half8*)&Bs[(wn * 64 + ni * 16 + r) * LDSTR + ko];
#pragma unroll
      for (int mi = 0; mi < 4; ++mi)
#pragma unroll
        for (int ni = 0; ni < 4; ++ni)
          acc[mi][ni] = __builtin_amdgcn_mfma_f32_16x16x32_f16(af[mi], bf[ni], acc[mi][ni], 0, 0, 0);
    }
  }

#pragma unroll
  for (int mi = 0; mi < 4; ++mi) {
    const int mb = blockM + wm * 64 + mi * 16 + quad * 4;
#pragma unroll
    for (int ni = 0; ni < 4; ++ni) {
      const int n = n0 + wn * 64 + ni * 16 + r;
      const float bias = (n < 256) ? boff[n] : battn[n - 256];
#pragma unroll
      for (int reg = 0; reg < 4; ++reg)
        logits[(size_t)(mb + reg) * NLOG + n] = acc[mi][ni][reg] + bias;
    }
  }
}

// ---------------- K3: sampling (branchless, 4 lanes per (q,h)) ----------------
// grid (256, 8, 2) = (q-tile of 64, head, batch); block 256.
// thread: c4 = tid&3 -> channels c4*8..c4*8+7 (half8 taps); qi = tid>>2.
__global__ __launch_bounds__(256) void sample_kernel(
    const _Float16* __restrict__ vh, const float* __restrict__ refp,
    const float* __restrict__ logits, float* __restrict__ out) {
  const int qt = blockIdx.x, h = blockIdx.y, b = blockIdx.z;
  const int tid = threadIdx.x;
  const int c4 = tid & 3;
  const int qi = tid >> 2;
  const int q  = qt * 64 + qi;
  const size_t bq = (size_t)b * NQ + q;
  const float* lg = logits + bq * NLOG;

  // attn softmax over 16 (l*4+p) logits
  float4v al4[4];
#pragma unroll
  for (int i = 0; i < 4; ++i)
    al4[i] = *(const float4v*)(lg + 256 + h * 16 + i * 4);
  float mx = -1e30f;
#pragma unroll
  for (int i = 0; i < 4; ++i)
#pragma unroll
    for (int j = 0; j < 4; ++j) mx = fmaxf(mx, al4[i][j]);
  float ssum = 0.f;
#pragma unroll
  for (int i = 0; i < 4; ++i)
#pragma unroll
    for (int j = 0; j < 4; ++j) {
      float e = __expf(al4[i][j] - mx);
      al4[i][j] = e;
      ssum += e;
    }
  const float inv = 1.0f / ssum;

  // offsets (32 floats, layout l*8+p*2+xy) and reference points (8 floats)
  float4v offv[8];
#pragma unroll
  for (int i = 0; i < 8; ++i)
    offv[i] = *(const float4v*)(lg + h * 32 + i * 4);
  float4v rp0 = *(const float4v*)(refp + bq * 8);
  float4v rp1 = *(const float4v*)(refp + bq * 8 + 4);
  const float rpx[4] = {rp0[0], rp0[2], rp1[0], rp1[2]};
  const float rpy[4] = {rp0[1], rp0[3], rp1[1], rp1[3]};

  const _Float16* vb = vh + (size_t)b * NTOK * 256 + h * 32 + c4 * 8;
  float4v acc0 = (float4v){0.f, 0.f, 0.f, 0.f};
  float4v acc1 = (float4v){0.f, 0.f, 0.f, 0.f};

  const int base[4] = {0, 16384, 20480, 21504};

#pragma unroll
  for (int l = 0; l < 4; ++l) {
    const int   W  = 128 >> l;
    const float fW = (float)W;
    const _Float16* vlev = vb + (size_t)base[l] * 256;
#pragma unroll
    for (int p = 0; p < 4; ++p) {
      const float a  = al4[l][p] * inv;
      const float ox = offv[l * 2 + (p >> 1)][(p & 1) * 2];
      const float oy = offv[l * 2 + (p >> 1)][(p & 1) * 2 + 1];
      // (ref + off/shape)*2-1 through grid_sample == ref*W + off - 0.5
      const float x = rpx[p] * fW + ox - 0.5f;
      const float y = rpy[p] * fW + oy - 0.5f;
      const float xf = floorf(x), yf = floorf(y);
      const float fx = x - xf, fy = y - yf;
      const int ix = (int)xf, iy = (int)yf;
      // clamped addresses, validity folded into weights (zeros padding)
      const int ix0 = min(max(ix, 0), W - 1);
      const int ix1 = min(max(ix + 1, 0), W - 1);
      const int iy0 = min(max(iy, 0), W - 1);
      const int iy1 = min(max(iy + 1, 0), W - 1);
      const float wx0 = ((unsigned)ix       < (unsigned)W) ? 1.f - fx : 0.f;
      const float wx1 = ((unsigned)(ix + 1) < (unsigned)W) ? fx       : 0.f;
      const float wy0 = ((unsigned)iy       < (unsigned)W) ? 1.f - fy : 0.f;
      const float wy1 = ((unsigned)(iy + 1) < (unsigned)W) ? fy       : 0.f;
      const float w00 = a * wx0 * wy0, w01 = a * wx1 * wy0;
      const float w10 = a * wx0 * wy1, w11 = a * wx1 * wy1;
      const _Float16* r0 = vlev + (size_t)(iy0 * W) * 256;
      const _Float16* r1 = vlev + (size_t)(iy1 * W) * 256;
      half8 t00 = *(const half8*)(r0 + ix0 * 256);
      half8 t01 = *(const half8*)(r0 + ix1 * 256);
      half8 t10 = *(const half8*)(r1 + ix0 * 256);
      half8 t11 = *(const half8*)(r1 + ix1 * 256);
#pragma unroll
      for (int j = 0; j < 4; ++j) {
        acc0[j] += w00 * (float)t00[j]     + w01 * (float)t01[j]
                 + w10 * (float)t10[j]     + w11 * (float)t11[j];
        acc1[j] += w00 * (float)t00[j + 4] + w01 * (float)t01[j + 4]
                 + w10 * (float)t10[j + 4] + w11 * (float)t11[j + 4];
      }
    }
  }

  // LDS transpose -> coalesced out[b][h*32+c][q]
  __shared__ float sm[32][65];
#pragma unroll
  for (int j = 0; j < 4; ++j) {
    sm[c4 * 8 + j][qi]     = acc0[j];
    sm[c4 * 8 + 4 + j][qi] = acc1[j];
  }
  __syncthreads();
  const size_t obase = ((size_t)b * 256 + h * 32) * NQ + qt * 64;
#pragma unroll
  for (int i = 0; i < 8; ++i) {
    const int idx = i * 256 + tid;
    const int c = idx >> 6, qq = idx & 63;
    out[obase + (size_t)c * NQ + qq] = sm[c][qq];
  }
}

extern "C" void kernel_launch(void* const* d_in, const int* in_sizes, int n_in,
                              void* d_out, int out_size, void* d_ws, size_t ws_size,
                              hipStream_t stream) {
  const float* query = (const float*)d_in[0];
  const float* value = (const float*)d_in[1];
  const float* refp  = (const float*)d_in[2];
  const float* Woff  = (const float*)d_in[3];
  const float* boff  = (const float*)d_in[4];
  const float* Wattn = (const float*)d_in[5];
  const float* battn = (const float*)d_in[6];
  float* out = (float*)d_out;

  char* ws = (char*)d_ws;
  _Float16* vh     = (_Float16*)ws;                    // 22,282,240 B
  _Float16* wh     = (_Float16*)(ws + 22282240);       //    196,608 B
  float*    logits = (float*)(ws + 22478848);          // 50,331,648 B

  convert_kernel<<<10976, 256, 0, stream>>>(value, Woff, Wattn, vh, wh);
  gemm_kernel<<<dim3(256, 3), 256, 0, stream>>>(query, wh, boff, battn, logits);
  sample_kernel<<<dim3(256, 8, 2), 256, 0, stream>>>(vh, refp, logits, out);
}